// Round 1
// 1122.052 us; speedup vs baseline: 1.6461x; 1.6461x over previous
//
#include <hip/hip_runtime.h>

// out[d] = prod_{e: dst[e]==d} (1 - x[src[e]] * p[e] * w)  + sl * x[d]
//
// R5: counters showed WRITE_SIZE == 32M x 32B exactly -> every global fp32
// atomic still issues a 32B memory-side transaction; rate-limited at
// ~20.8 G atomics/s (~1/cycle/XCD). No atomic variant fixes that, so this
// version ELIMINATES global atomics:
//   p2_bucket : per-block counting sort of 8192 edges into K=ceil(N/8192)
//               destination buckets; exact per-(block,bucket) segments in a
//               dense queue (no overflow, no global atomics).
//   p3_accum  : per (bucket, slice) block accumulates its segments into a
//               32KB LDS accumulator with ds_add_f32, writes partials.
//   finalize_q: sum slice partials, exp2, + sl*x.
// Falls back to the verified R4 path if the workspace is too small.

#if defined(__has_builtin) && __has_builtin(__builtin_amdgcn_exp2f)
#define EXP2F(v) __builtin_amdgcn_exp2f(v)
#else
#define EXP2F(v) exp2f(v)
#endif

#define BLK 256
#define NB_SHIFT 13
#define NB (1 << NB_SHIFT)   // 8192 nodes per bucket (32KB fp32 LDS accumulator)
#define EPB2 8192            // edges per p2 block
#define MAXK 256             // max buckets supported (n_nodes <= 2M)
#define HDRCHUNK 1024

// ---------------------------------------------------------------- old path --
__device__ __forceinline__ unsigned xcc_id() {
    return __builtin_amdgcn_s_getreg((31 << 11) | 20) & 7u;
}
__device__ __forceinline__ void atomic_fadd_l2(float* p, float v) {
    asm volatile("global_atomic_add_f32 %0, %1, off" :: "v"(p), "v"(v) : "memory");
}
__device__ __forceinline__ void atomic_fadd_agent(float* p, float v) {
    unsafeAtomicAdd(p, v);
}

__global__ void init_zero(float* __restrict__ ws, int n) {
    int i = blockIdx.x * blockDim.x + threadIdx.x;
    if (i < n) ws[i] = 0.0f;
}

template <bool USE_L2>
__global__ __launch_bounds__(256) void edge_scatter(
        const float* __restrict__ x,
        const int* __restrict__ src,
        const int* __restrict__ dst,
        const float* __restrict__ probs,
        const float* __restrict__ w_ptr,
        float* __restrict__ logsum,
        int n_nodes, int n_e4) {
    const float w = w_ptr[0];
    float* ls = USE_L2 ? (logsum + (size_t)xcc_id() * (size_t)n_nodes) : logsum;
    int i = blockIdx.x * blockDim.x + threadIdx.x;
    if (i >= n_e4) return;
    int4   s = ((const int4*)src)[i];
    int4   d = ((const int4*)dst)[i];
    float4 p = ((const float4*)probs)[i];
    float m0 = __log2f(1.0f - x[s.x] * p.x * w);
    float m1 = __log2f(1.0f - x[s.y] * p.y * w);
    float m2 = __log2f(1.0f - x[s.z] * p.z * w);
    float m3 = __log2f(1.0f - x[s.w] * p.w * w);
    if (USE_L2) {
        atomic_fadd_l2(&ls[d.x], m0); atomic_fadd_l2(&ls[d.y], m1);
        atomic_fadd_l2(&ls[d.z], m2); atomic_fadd_l2(&ls[d.w], m3);
    } else {
        atomic_fadd_agent(&ls[d.x], m0); atomic_fadd_agent(&ls[d.y], m1);
        atomic_fadd_agent(&ls[d.z], m2); atomic_fadd_agent(&ls[d.w], m3);
    }
}

template <bool USE_L2>
__global__ void edge_scatter_tail(
        const float* __restrict__ x,
        const int* __restrict__ src,
        const int* __restrict__ dst,
        const float* __restrict__ probs,
        const float* __restrict__ w_ptr,
        float* __restrict__ logsum,
        int n_nodes, int start, int n_edges) {
    const float w = w_ptr[0];
    float* ls = USE_L2 ? (logsum + (size_t)xcc_id() * (size_t)n_nodes) : logsum;
    int i = start + blockIdx.x * blockDim.x + threadIdx.x;
    if (i >= n_edges) return;
    float m = __log2f(1.0f - x[src[i]] * probs[i] * w);
    if (USE_L2) atomic_fadd_l2(&ls[dst[i]], m);
    else        atomic_fadd_agent(&ls[dst[i]], m);
}

__global__ void finalize8(const float* __restrict__ x,
                          const float* __restrict__ sl_ptr,
                          const float* __restrict__ logsum,
                          float* __restrict__ out, int n) {
    int i = blockIdx.x * blockDim.x + threadIdx.x;
    if (i >= n) return;
    float s = 0.0f;
    #pragma unroll
    for (int r = 0; r < 8; ++r) s += logsum[(size_t)r * n + i];
    out[i] = EXP2F(s) + sl_ptr[0] * x[i];
}

__global__ void finalize1(const float* __restrict__ x,
                          const float* __restrict__ sl_ptr,
                          const float* __restrict__ logsum,
                          float* __restrict__ out, int n) {
    int i = blockIdx.x * blockDim.x + threadIdx.x;
    if (i < n) out[i] = EXP2F(logsum[i]) + sl_ptr[0] * x[i];
}

// ---------------------------------------------------------------- new path --

// Pass 2: per-block counting sort of EPB2 edges into K buckets.
__global__ __launch_bounds__(256) void p2_bucket(
        const float* __restrict__ x,
        const int* __restrict__ src,
        const int* __restrict__ dstp,
        const float* __restrict__ probs,
        const float* __restrict__ w_ptr,
        unsigned* __restrict__ seg_off,   // [K][G]
        unsigned* __restrict__ seg_cnt,   // [K][G]
        uint2* __restrict__ queue,        // [G][EPB2]
        int ebase, int ecount, int K, int G, int vec_ok) {
    __shared__ unsigned short loc[EPB2]; // dst & (NB-1)
    __shared__ unsigned char  bkt[EPB2]; // dst >> NB_SHIFT (K <= 256)
    __shared__ unsigned cnt[MAXK];
    __shared__ unsigned cur[MAXK];
    __shared__ unsigned wsum[4];
    const int b = blockIdx.x;
    const int t = threadIdx.x;

    for (int i = t; i < K; i += BLK) cnt[i] = 0;
    __syncthreads();

    const int begin = ebase + b * EPB2;
    const int end   = min(begin + EPB2, ebase + ecount);

    // sweep 1: read dst, stash (bucket, local), count
    auto stash1 = [&](int e) {
        const int dv = dstp[e];
        const int j  = e - begin;
        const unsigned kk = (unsigned)dv >> NB_SHIFT;
        bkt[j] = (unsigned char)kk;
        loc[j] = (unsigned short)(dv & (NB - 1));
        atomicAdd(&cnt[kk], 1u);
    };
    if (vec_ok) {
        for (int e0 = begin + t * 4; e0 < end; e0 += BLK * 4) {
            if (e0 + 4 <= end) {
                const int4 d = *(const int4*)(dstp + e0);
                const int j = e0 - begin;
                const unsigned k0 = (unsigned)d.x >> NB_SHIFT;
                const unsigned k1 = (unsigned)d.y >> NB_SHIFT;
                const unsigned k2 = (unsigned)d.z >> NB_SHIFT;
                const unsigned k3 = (unsigned)d.w >> NB_SHIFT;
                bkt[j+0] = (unsigned char)k0; loc[j+0] = (unsigned short)(d.x & (NB-1));
                bkt[j+1] = (unsigned char)k1; loc[j+1] = (unsigned short)(d.y & (NB-1));
                bkt[j+2] = (unsigned char)k2; loc[j+2] = (unsigned short)(d.z & (NB-1));
                bkt[j+3] = (unsigned char)k3; loc[j+3] = (unsigned short)(d.w & (NB-1));
                atomicAdd(&cnt[k0], 1u); atomicAdd(&cnt[k1], 1u);
                atomicAdd(&cnt[k2], 1u); atomicAdd(&cnt[k3], 1u);
            } else {
                for (int e = e0; e < end; ++e) stash1(e);
            }
        }
    } else {
        for (int e0 = begin + t * 4; e0 < end; e0 += BLK * 4) {
            const int ee = min(e0 + 4, end);
            for (int e = e0; e < ee; ++e) stash1(e);
        }
    }
    __syncthreads();

    // exclusive block scan of cnt[0..K) (K <= 256, 4 waves)
    {
        const unsigned v = (t < K) ? cnt[t] : 0u;
        unsigned xs = v;
        #pragma unroll
        for (int o = 1; o < 64; o <<= 1) {
            const unsigned y = __shfl_up(xs, o, 64);
            if ((t & 63) >= o) xs += y;
        }
        if ((t & 63) == 63) wsum[t >> 6] = xs;
        __syncthreads();
        unsigned woff = 0;
        for (int wv = 0; wv < (t >> 6); ++wv) woff += wsum[wv];
        const unsigned ex = xs + woff - v;
        if (t < K) {
            cur[t] = ex;
            seg_off[(size_t)t * G + b] = ex;
            seg_cnt[(size_t)t * G + b] = v;
        }
    }
    __syncthreads();

    // sweep 2: read src/probs, compute log-message, place grouped by bucket
    const float w = w_ptr[0];
    auto place1 = [&](int e) {
        const int j = e - begin;
        const float m = __log2f(1.0f - x[src[e]] * probs[e] * w);
        const unsigned kk = bkt[j];
        const unsigned r  = atomicAdd(&cur[kk], 1u);
        queue[(size_t)b * EPB2 + r] = make_uint2((unsigned)loc[j], __float_as_uint(m));
    };
    if (vec_ok) {
        for (int e0 = begin + t * 4; e0 < end; e0 += BLK * 4) {
            if (e0 + 4 <= end) {
                const int4   sv = *(const int4*)(src + e0);
                const float4 pv = *(const float4*)(probs + e0);
                const int j = e0 - begin;
                const float m0 = __log2f(1.0f - x[sv.x] * pv.x * w);
                const float m1 = __log2f(1.0f - x[sv.y] * pv.y * w);
                const float m2 = __log2f(1.0f - x[sv.z] * pv.z * w);
                const float m3 = __log2f(1.0f - x[sv.w] * pv.w * w);
                const unsigned k0 = bkt[j+0], k1 = bkt[j+1], k2 = bkt[j+2], k3 = bkt[j+3];
                const unsigned r0 = atomicAdd(&cur[k0], 1u);
                queue[(size_t)b * EPB2 + r0] = make_uint2((unsigned)loc[j+0], __float_as_uint(m0));
                const unsigned r1 = atomicAdd(&cur[k1], 1u);
                queue[(size_t)b * EPB2 + r1] = make_uint2((unsigned)loc[j+1], __float_as_uint(m1));
                const unsigned r2 = atomicAdd(&cur[k2], 1u);
                queue[(size_t)b * EPB2 + r2] = make_uint2((unsigned)loc[j+2], __float_as_uint(m2));
                const unsigned r3 = atomicAdd(&cur[k3], 1u);
                queue[(size_t)b * EPB2 + r3] = make_uint2((unsigned)loc[j+3], __float_as_uint(m3));
            } else {
                for (int e = e0; e < end; ++e) place1(e);
            }
        }
    } else {
        for (int e0 = begin + t * 4; e0 < end; e0 += BLK * 4) {
            const int ee = min(e0 + 4, end);
            for (int e = e0; e < ee; ++e) place1(e);
        }
    }
}

// Pass 3: block (bucket k, slice s) accumulates segments b = s, s+s3, ...
// into a 32KB LDS accumulator via ds_add_f32; writes/accumulates partials.
__global__ __launch_bounds__(256) void p3_accum(
        const uint2* __restrict__ queue,
        const unsigned* __restrict__ seg_off,
        const unsigned* __restrict__ seg_cnt,
        float* __restrict__ partial,   // [K*s3][NB]
        int G, int s3) {
    __shared__ float acc[NB];
    __shared__ unsigned hoff[HDRCHUNK];
    __shared__ unsigned hcnt[HDRCHUNK];
    const int t = threadIdx.x;
    const int k = blockIdx.x / s3;
    const int s = blockIdx.x % s3;
    for (int i = t; i < NB; i += BLK) acc[i] = 0.0f;
    const unsigned* po = seg_off + (size_t)k * G;
    const unsigned* pc = seg_cnt + (size_t)k * G;
    const int nb = (s < G) ? (G - s + s3 - 1) / s3 : 0;
    for (int c0 = 0; c0 < nb; c0 += HDRCHUNK) {
        const int cn = min(HDRCHUNK, nb - c0);
        __syncthreads();
        for (int i = t; i < cn; i += BLK) {      // stage headers -> no pointer chase
            const int bb = s + (c0 + i) * s3;
            hoff[i] = po[bb];
            hcnt[i] = pc[bb];
        }
        __syncthreads();
        for (int j = 0; j < cn; ++j) {
            const unsigned n = hcnt[j];
            if (!n) continue;
            const int bb = s + (c0 + j) * s3;
            const uint2* q = queue + (size_t)bb * EPB2 + hoff[j];
            for (unsigned i = t; i < n; i += BLK) {
                const uint2 e = q[i];
                atomicAdd(&acc[e.x], __uint_as_float(e.y));   // ds_add_f32
            }
        }
    }
    __syncthreads();
    float* p = partial + (size_t)blockIdx.x * NB;
    for (int i = t; i < NB; i += BLK) p[i] += acc[i];   // accumulate across rounds
}

__global__ __launch_bounds__(256) void finalize_q(
        const float* __restrict__ x,
        const float* __restrict__ sl_ptr,
        const float* __restrict__ partial,
        float* __restrict__ out, int n, int s3) {
    int i = blockIdx.x * blockDim.x + threadIdx.x;
    if (i >= n) return;
    const int k = i >> NB_SHIFT;
    const int l = i & (NB - 1);
    const float* p = partial + ((size_t)k * s3) * NB + l;
    float ssum = 0.0f;
    for (int r = 0; r < s3; ++r) ssum += p[(size_t)r * NB];
    out[i] = EXP2F(ssum) + sl_ptr[0] * x[i];
}

// ---------------------------------------------------------------- host -----

static inline size_t alignup256(size_t v) { return (v + 255) & ~(size_t)255; }

extern "C" void kernel_launch(void* const* d_in, const int* in_sizes, int n_in,
                              void* d_out, int out_size, void* d_ws, size_t ws_size,
                              hipStream_t stream) {
    const float* x          = (const float*)d_in[0];   // (N,1) fp32
    const int*   edge_index = (const int*)  d_in[1];   // (2,E) int32
    const float* probs      = (const float*)d_in[2];   // (E,)  fp32
    const float* w          = (const float*)d_in[3];   // (1,)
    const float* sl         = (const float*)d_in[4];   // (1,)

    const int n_nodes = in_sizes[0];
    const int n_edges = in_sizes[1] / 2;
    const int* src = edge_index;
    const int* dst = edge_index + n_edges;

    const int K = (n_nodes + NB - 1) >> NB_SHIFT;

    // Fit search: smallest round count R (queue = E/R entries), largest slice
    // count s3 that fits the workspace.
    int R = 0, s3 = 0, G0 = 0;
    long long Er = 0;
    size_t off_soff = 0, off_scnt = 0, off_queue = 0;
    if (n_nodes > 0 && K >= 1 && K <= MAXK) {
        const int s3cand[4] = {8, 4, 2, 1};
        for (int r = 1; r <= 32 && !R; ++r) {
            long long er = (((long long)n_edges + r - 1) / r + 3) & ~3LL;
            if (er < 4) er = 4;
            int g = (int)((er + EPB2 - 1) / EPB2);
            if (g < 1) g = 1;
            for (int ci = 0; ci < 4; ++ci) {
                const int cs3 = s3cand[ci];
                const size_t pb = (size_t)K * cs3 * NB * sizeof(float);
                const size_t sb = (size_t)K * g * sizeof(unsigned);
                const size_t o1 = alignup256(pb);
                const size_t o2 = o1 + alignup256(sb);
                const size_t o3 = o2 + alignup256(sb);
                const size_t tot = o3 + (size_t)g * EPB2 * sizeof(uint2);
                if (tot <= ws_size) {
                    R = r; s3 = cs3; G0 = g; Er = er;
                    off_soff = o1; off_scnt = o2; off_queue = o3;
                    break;
                }
            }
        }
    }

    if (R > 0) {
        char* wsb = (char*)d_ws;
        float*    partial_p = (float*)wsb;
        unsigned* seg_off_p = (unsigned*)(wsb + off_soff);
        unsigned* seg_cnt_p = (unsigned*)(wsb + off_scnt);
        uint2*    queue_p   = (uint2*)(wsb + off_queue);

        const int np = K * s3 * NB;
        init_zero<<<(np + 255) / 256, 256, 0, stream>>>(partial_p, np);

        const int vec_ok = ((n_edges & 3) == 0) ? 1 : 0;
        for (int r = 0; r < R; ++r) {
            const long long eb = (long long)r * Er;
            if (eb >= n_edges) break;
            const long long rem = (long long)n_edges - eb;
            const int ec = (int)(rem < Er ? rem : Er);
            const int g = (ec + EPB2 - 1) / EPB2;
            p2_bucket<<<g, BLK, 0, stream>>>(
                x, src, dst, probs, w, seg_off_p, seg_cnt_p, queue_p,
                (int)eb, ec, K, g, vec_ok);
            p3_accum<<<K * s3, BLK, 0, stream>>>(
                queue_p, seg_off_p, seg_cnt_p, partial_p, g, s3);
        }
        finalize_q<<<(n_nodes + 255) / 256, 256, 0, stream>>>(
            x, sl, partial_p, (float*)d_out, n_nodes, s3);
        (void)G0;
        return;
    }

    // ---------------- fallback: verified R4 path ----------------
    float* logsum = (float*)d_ws;
    const bool use_l2 = ws_size >= (size_t)8 * (size_t)n_nodes * sizeof(float);
    const int n_ls = use_l2 ? 8 * n_nodes : n_nodes;

    init_zero<<<(n_ls + 255) / 256, 256, 0, stream>>>(logsum, n_ls);

    const int e4 = n_edges / 4;
    const int tail_start = e4 * 4;
    const int tail = n_edges - tail_start;

    if (use_l2) {
        if (e4 > 0)
            edge_scatter<true><<<(e4 + 255) / 256, 256, 0, stream>>>(
                x, src, dst, probs, w, logsum, n_nodes, e4);
        if (tail > 0)
            edge_scatter_tail<true><<<(tail + 255) / 256, 256, 0, stream>>>(
                x, src, dst, probs, w, logsum, n_nodes, tail_start, n_edges);
        finalize8<<<(n_nodes + 255) / 256, 256, 0, stream>>>(
            x, sl, logsum, (float*)d_out, n_nodes);
    } else {
        if (e4 > 0)
            edge_scatter<false><<<(e4 + 255) / 256, 256, 0, stream>>>(
                x, src, dst, probs, w, logsum, n_nodes, e4);
        if (tail > 0)
            edge_scatter_tail<false><<<(tail + 255) / 256, 256, 0, stream>>>(
                x, src, dst, probs, w, logsum, n_nodes, tail_start, n_edges);
        finalize1<<<(n_nodes + 255) / 256, 256, 0, stream>>>(
            x, sl, logsum, (float*)d_out, n_nodes);
    }
}

// Round 2
// 972.695 us; speedup vs baseline: 1.8989x; 1.1535x over previous
//
#include <hip/hip_runtime.h>

// out[d] = prod_{e: dst[e]==d} (1 - x[src[e]] * p[e] * w)  + sl * x[d]
//
// R6: bucket-major queue via exact global binning (no global atomics):
//   k_hist     : per-block LDS histogram of dst buckets -> hist[k][b]
//   k_scan_row : exclusive scan of each bucket row (in-place) + row totals
//   k_scan_bkt : exclusive scan of bucket totals -> bucket slab bases
//   k_scatter  : ONE fused sweep: read dst/src/probs, m = log2(1-x*p*w),
//                rank = ds_add_rtn on cur[k] (seeded with global run start),
//                store (loc,m) to its exact global slot. Minimal LDS.
//   k_accum    : bucket slab is contiguous -> coalesced streams into 32KB
//                LDS accumulator (ds_add_f32), full-wave occupancy.
//   k_final    : sum slice partials, exp2, + sl*x.
// R5's p2 (two-sweep + 24KB stash + block-major queue) and p3 (segment
// chasing, partial waves) both dissolve. Fallbacks: multi-round if ws is
// small; R4 atomic path if ws is tiny.

#if defined(__has_builtin) && __has_builtin(__builtin_amdgcn_exp2f)
#define EXP2F(v) __builtin_amdgcn_exp2f(v)
#else
#define EXP2F(v) exp2f(v)
#endif

#define BLK 256
#define NB_SHIFT 13
#define NB (1 << NB_SHIFT)   // 8192 nodes per bucket (32KB fp32 LDS accumulator)
#define EPB 16384            // edges per hist/scatter block
#define MAXK 256             // max buckets (n_nodes <= 2M)

// ---------------------------------------------------------------- old path --
__device__ __forceinline__ unsigned xcc_id() {
    return __builtin_amdgcn_s_getreg((31 << 11) | 20) & 7u;
}
__device__ __forceinline__ void atomic_fadd_l2(float* p, float v) {
    asm volatile("global_atomic_add_f32 %0, %1, off" :: "v"(p), "v"(v) : "memory");
}
__device__ __forceinline__ void atomic_fadd_agent(float* p, float v) {
    unsafeAtomicAdd(p, v);
}

__global__ void init_zero(float* __restrict__ ws, int n) {
    int i = blockIdx.x * blockDim.x + threadIdx.x;
    if (i < n) ws[i] = 0.0f;
}

template <bool USE_L2>
__global__ __launch_bounds__(256) void edge_scatter(
        const float* __restrict__ x,
        const int* __restrict__ src,
        const int* __restrict__ dst,
        const float* __restrict__ probs,
        const float* __restrict__ w_ptr,
        float* __restrict__ logsum,
        int n_nodes, int n_e4) {
    const float w = w_ptr[0];
    float* ls = USE_L2 ? (logsum + (size_t)xcc_id() * (size_t)n_nodes) : logsum;
    int i = blockIdx.x * blockDim.x + threadIdx.x;
    if (i >= n_e4) return;
    int4   s = ((const int4*)src)[i];
    int4   d = ((const int4*)dst)[i];
    float4 p = ((const float4*)probs)[i];
    float m0 = __log2f(1.0f - x[s.x] * p.x * w);
    float m1 = __log2f(1.0f - x[s.y] * p.y * w);
    float m2 = __log2f(1.0f - x[s.z] * p.z * w);
    float m3 = __log2f(1.0f - x[s.w] * p.w * w);
    if (USE_L2) {
        atomic_fadd_l2(&ls[d.x], m0); atomic_fadd_l2(&ls[d.y], m1);
        atomic_fadd_l2(&ls[d.z], m2); atomic_fadd_l2(&ls[d.w], m3);
    } else {
        atomic_fadd_agent(&ls[d.x], m0); atomic_fadd_agent(&ls[d.y], m1);
        atomic_fadd_agent(&ls[d.z], m2); atomic_fadd_agent(&ls[d.w], m3);
    }
}

template <bool USE_L2>
__global__ void edge_scatter_tail(
        const float* __restrict__ x,
        const int* __restrict__ src,
        const int* __restrict__ dst,
        const float* __restrict__ probs,
        const float* __restrict__ w_ptr,
        float* __restrict__ logsum,
        int n_nodes, int start, int n_edges) {
    const float w = w_ptr[0];
    float* ls = USE_L2 ? (logsum + (size_t)xcc_id() * (size_t)n_nodes) : logsum;
    int i = start + blockIdx.x * blockDim.x + threadIdx.x;
    if (i >= n_edges) return;
    float m = __log2f(1.0f - x[src[i]] * probs[i] * w);
    if (USE_L2) atomic_fadd_l2(&ls[dst[i]], m);
    else        atomic_fadd_agent(&ls[dst[i]], m);
}

__global__ void finalize8(const float* __restrict__ x,
                          const float* __restrict__ sl_ptr,
                          const float* __restrict__ logsum,
                          float* __restrict__ out, int n) {
    int i = blockIdx.x * blockDim.x + threadIdx.x;
    if (i >= n) return;
    float s = 0.0f;
    #pragma unroll
    for (int r = 0; r < 8; ++r) s += logsum[(size_t)r * n + i];
    out[i] = EXP2F(s) + sl_ptr[0] * x[i];
}

__global__ void finalize1(const float* __restrict__ x,
                          const float* __restrict__ sl_ptr,
                          const float* __restrict__ logsum,
                          float* __restrict__ out, int n) {
    int i = blockIdx.x * blockDim.x + threadIdx.x;
    if (i < n) out[i] = EXP2F(logsum[i]) + sl_ptr[0] * x[i];
}

// ---------------------------------------------------------------- new path --

// Step 1: per-block histogram of dst buckets. hist[k*G0 + b].
__global__ __launch_bounds__(256) void k_hist(
        const int* __restrict__ dstp,
        unsigned* __restrict__ hist,
        int ebase, int ecount, int K, int G0, int vec_ok) {
    __shared__ unsigned h[MAXK];
    const int b = blockIdx.x;
    const int t = threadIdx.x;
    for (int i = t; i < K; i += BLK) h[i] = 0;
    __syncthreads();
    const int begin = ebase + b * EPB;
    const int end   = min(begin + EPB, ebase + ecount);
    if (vec_ok) {
        for (int e0 = begin + t * 4; e0 < end; e0 += BLK * 4) {
            if (e0 + 4 <= end) {
                const int4 d = *(const int4*)(dstp + e0);
                atomicAdd(&h[(unsigned)d.x >> NB_SHIFT], 1u);
                atomicAdd(&h[(unsigned)d.y >> NB_SHIFT], 1u);
                atomicAdd(&h[(unsigned)d.z >> NB_SHIFT], 1u);
                atomicAdd(&h[(unsigned)d.w >> NB_SHIFT], 1u);
            } else {
                for (int e = e0; e < end; ++e)
                    atomicAdd(&h[(unsigned)dstp[e] >> NB_SHIFT], 1u);
            }
        }
    } else {
        for (int e0 = begin + t * 4; e0 < end; e0 += BLK * 4) {
            const int ee = min(e0 + 4, end);
            for (int e = e0; e < ee; ++e)
                atomicAdd(&h[(unsigned)dstp[e] >> NB_SHIFT], 1u);
        }
    }
    __syncthreads();
    for (int i = t; i < K; i += BLK) hist[(size_t)i * G0 + b] = h[i];
}

// Step 2a: in-place exclusive scan of each bucket row; row total -> btot[k].
__global__ __launch_bounds__(256) void k_scan_row(
        unsigned* __restrict__ hist, unsigned* __restrict__ btot,
        int G0, int Gr) {
    __shared__ unsigned wsum[4];
    __shared__ unsigned carry;
    const int k = blockIdx.x;
    const int t = threadIdx.x;
    unsigned* row = hist + (size_t)k * G0;
    if (t == 0) carry = 0;
    __syncthreads();
    for (int c0 = 0; c0 < Gr; c0 += BLK) {
        const unsigned v = (c0 + t < Gr) ? row[c0 + t] : 0u;
        unsigned xs = v;
        #pragma unroll
        for (int o = 1; o < 64; o <<= 1) {
            const unsigned y = __shfl_up(xs, o, 64);
            if ((t & 63) >= o) xs += y;
        }
        if ((t & 63) == 63) wsum[t >> 6] = xs;
        __syncthreads();
        unsigned woff = 0;
        for (int wv = 0; wv < (t >> 6); ++wv) woff += wsum[wv];
        const unsigned ex = xs + woff - v + carry;
        if (c0 + t < Gr) row[c0 + t] = ex;
        const unsigned ctot = wsum[0] + wsum[1] + wsum[2] + wsum[3];
        __syncthreads();
        if (t == 0) carry += ctot;
        __syncthreads();
    }
    if (t == 0) btot[k] = carry;
}

// Step 2b: exclusive scan of bucket totals -> bbase[k].
__global__ __launch_bounds__(256) void k_scan_bkt(
        const unsigned* __restrict__ btot, unsigned* __restrict__ bbase, int K) {
    __shared__ unsigned wsum[4];
    const int t = threadIdx.x;
    const unsigned v = (t < K) ? btot[t] : 0u;
    unsigned xs = v;
    #pragma unroll
    for (int o = 1; o < 64; o <<= 1) {
        const unsigned y = __shfl_up(xs, o, 64);
        if ((t & 63) >= o) xs += y;
    }
    if ((t & 63) == 63) wsum[t >> 6] = xs;
    __syncthreads();
    unsigned woff = 0;
    for (int wv = 0; wv < (t >> 6); ++wv) woff += wsum[wv];
    if (t < K) bbase[t] = xs + woff - v;
}

// Step 3: fused scatter. Single sweep over dst/src/probs; each (block,bucket)
// run start is exact: cur[k] = bbase[k] + base[k*G0 + b].
__global__ __launch_bounds__(256) void k_scatter(
        const float* __restrict__ x,
        const int* __restrict__ src,
        const int* __restrict__ dstp,
        const float* __restrict__ probs,
        const float* __restrict__ w_ptr,
        const unsigned* __restrict__ base,   // scanned hist
        const unsigned* __restrict__ bbase,
        uint2* __restrict__ queue,
        int ebase, int ecount, int K, int G0, int vec_ok) {
    __shared__ unsigned cur[MAXK];
    const int b = blockIdx.x;
    const int t = threadIdx.x;
    for (int i = t; i < K; i += BLK)
        cur[i] = bbase[i] + base[(size_t)i * G0 + b];
    __syncthreads();
    const float w = w_ptr[0];
    const int begin = ebase + b * EPB;
    const int end   = min(begin + EPB, ebase + ecount);
    auto one = [&](int e) {
        const int dv = dstp[e];
        const float m = __log2f(1.0f - x[src[e]] * probs[e] * w);
        const unsigned kk = (unsigned)dv >> NB_SHIFT;
        const unsigned r = atomicAdd(&cur[kk], 1u);
        queue[r] = make_uint2((unsigned)dv & (NB - 1), __float_as_uint(m));
    };
    if (vec_ok) {
        for (int e0 = begin + t * 4; e0 < end; e0 += BLK * 4) {
            if (e0 + 4 <= end) {
                const int4   d  = *(const int4*)(dstp + e0);
                const int4   sv = *(const int4*)(src + e0);
                const float4 pv = *(const float4*)(probs + e0);
                const float m0 = __log2f(1.0f - x[sv.x] * pv.x * w);
                const float m1 = __log2f(1.0f - x[sv.y] * pv.y * w);
                const float m2 = __log2f(1.0f - x[sv.z] * pv.z * w);
                const float m3 = __log2f(1.0f - x[sv.w] * pv.w * w);
                const unsigned r0 = atomicAdd(&cur[(unsigned)d.x >> NB_SHIFT], 1u);
                queue[r0] = make_uint2((unsigned)d.x & (NB - 1), __float_as_uint(m0));
                const unsigned r1 = atomicAdd(&cur[(unsigned)d.y >> NB_SHIFT], 1u);
                queue[r1] = make_uint2((unsigned)d.y & (NB - 1), __float_as_uint(m1));
                const unsigned r2 = atomicAdd(&cur[(unsigned)d.z >> NB_SHIFT], 1u);
                queue[r2] = make_uint2((unsigned)d.z & (NB - 1), __float_as_uint(m2));
                const unsigned r3 = atomicAdd(&cur[(unsigned)d.w >> NB_SHIFT], 1u);
                queue[r3] = make_uint2((unsigned)d.w & (NB - 1), __float_as_uint(m3));
            } else {
                for (int e = e0; e < end; ++e) one(e);
            }
        }
    } else {
        for (int e0 = begin + t * 4; e0 < end; e0 += BLK * 4) {
            const int ee = min(e0 + 4, end);
            for (int e = e0; e < ee; ++e) one(e);
        }
    }
}

// Step 4: bucket slab (contiguous!) -> 32KB LDS accumulator -> partial.
__global__ __launch_bounds__(256) void k_accum(
        const uint2* __restrict__ queue,
        const unsigned* __restrict__ btot,
        const unsigned* __restrict__ bbase,
        float* __restrict__ partial,   // [K*s3][NB]
        int s3, int first) {
    __shared__ float acc[NB];
    const int t = threadIdx.x;
    const int k = blockIdx.x / s3;
    const int s = blockIdx.x % s3;
    for (int i = t; i < NB; i += BLK) acc[i] = 0.0f;
    __syncthreads();
    const unsigned cnt = btot[k];
    const unsigned per = (cnt + s3 - 1) / s3;
    const unsigned lo = min((unsigned)s * per, cnt);
    const unsigned hi = min(lo + per, cnt);
    const uint2* q = queue + bbase[k];
    unsigned i = lo + t;
    for (; i + BLK < hi; i += 2 * BLK) {
        const uint2 e0 = q[i];
        const uint2 e1 = q[i + BLK];
        atomicAdd(&acc[e0.x], __uint_as_float(e0.y));
        atomicAdd(&acc[e1.x], __uint_as_float(e1.y));
    }
    for (; i < hi; i += BLK) {
        const uint2 e = q[i];
        atomicAdd(&acc[e.x], __uint_as_float(e.y));
    }
    __syncthreads();
    float* p = partial + (size_t)blockIdx.x * NB;
    if (first) { for (int j = t; j < NB; j += BLK) p[j] = acc[j]; }
    else       { for (int j = t; j < NB; j += BLK) p[j] += acc[j]; }
}

__global__ __launch_bounds__(256) void k_final(
        const float* __restrict__ x,
        const float* __restrict__ sl_ptr,
        const float* __restrict__ partial,
        float* __restrict__ out, int n, int s3) {
    int i = blockIdx.x * blockDim.x + threadIdx.x;
    if (i >= n) return;
    const int k = i >> NB_SHIFT;
    const int l = i & (NB - 1);
    const float* p = partial + ((size_t)k * s3) * NB + l;
    float ssum = 0.0f;
    for (int r = 0; r < s3; ++r) ssum += p[(size_t)r * NB];
    out[i] = EXP2F(ssum) + sl_ptr[0] * x[i];
}

// ---------------------------------------------------------------- host -----

static inline size_t alignup256(size_t v) { return (v + 255) & ~(size_t)255; }

extern "C" void kernel_launch(void* const* d_in, const int* in_sizes, int n_in,
                              void* d_out, int out_size, void* d_ws, size_t ws_size,
                              hipStream_t stream) {
    const float* x          = (const float*)d_in[0];   // (N,1) fp32
    const int*   edge_index = (const int*)  d_in[1];   // (2,E) int32
    const float* probs      = (const float*)d_in[2];   // (E,)  fp32
    const float* w          = (const float*)d_in[3];   // (1,)
    const float* sl         = (const float*)d_in[4];   // (1,)

    const int n_nodes = in_sizes[0];
    const int n_edges = in_sizes[1] / 2;
    const int* src = edge_index;
    const int* dst = edge_index + n_edges;

    const int K = (n_nodes + NB - 1) >> NB_SHIFT;

    // Fit search: smallest round count R, then largest slice count s3.
    int R = 0, s3 = 0, G0 = 0;
    long long Er = 0;
    size_t off_hist = 0, off_btot = 0, off_bbase = 0, off_queue = 0;
    if (n_nodes > 0 && n_edges > 0 && K >= 1 && K <= MAXK) {
        const int s3cand[5] = {16, 8, 4, 2, 1};
        for (int r = 1; r <= 64 && !R; ++r) {
            long long er = (((long long)n_edges + r - 1) / r + 3) & ~3LL;
            if (er < 4) er = 4;
            int g = (int)((er + EPB - 1) / EPB);
            if (g < 1) g = 1;
            for (int ci = 0; ci < 5; ++ci) {
                const int cs3 = s3cand[ci];
                const size_t pb = (size_t)K * cs3 * NB * sizeof(float);
                const size_t hb = (size_t)K * g * sizeof(unsigned);
                const size_t kb = (size_t)K * sizeof(unsigned);
                const size_t o1 = alignup256(pb);                // hist
                const size_t o2 = o1 + alignup256(hb);           // btot
                const size_t o3 = o2 + alignup256(kb);           // bbase
                const size_t o4 = o3 + alignup256(kb);           // queue
                const size_t tot = o4 + (size_t)er * sizeof(uint2);
                if (tot <= ws_size) {
                    R = r; s3 = cs3; G0 = g; Er = er;
                    off_hist = o1; off_btot = o2; off_bbase = o3; off_queue = o4;
                    break;
                }
            }
        }
    }

    if (R > 0) {
        char* wsb = (char*)d_ws;
        float*    partial_p = (float*)wsb;
        unsigned* hist_p    = (unsigned*)(wsb + off_hist);
        unsigned* btot_p    = (unsigned*)(wsb + off_btot);
        unsigned* bbase_p   = (unsigned*)(wsb + off_bbase);
        uint2*    queue_p   = (uint2*)(wsb + off_queue);

        const int vec_ok = ((n_edges & 3) == 0) ? 1 : 0;
        for (int r = 0; r < R; ++r) {
            const long long eb = (long long)r * Er;
            if (eb >= n_edges) break;
            const long long rem = (long long)n_edges - eb;
            const int ec = (int)(rem < Er ? rem : Er);
            const int g = (ec + EPB - 1) / EPB;
            k_hist<<<g, BLK, 0, stream>>>(dst, hist_p, (int)eb, ec, K, G0, vec_ok);
            k_scan_row<<<K, BLK, 0, stream>>>(hist_p, btot_p, G0, g);
            k_scan_bkt<<<1, BLK, 0, stream>>>(btot_p, bbase_p, K);
            k_scatter<<<g, BLK, 0, stream>>>(
                x, src, dst, probs, w, hist_p, bbase_p, queue_p,
                (int)eb, ec, K, G0, vec_ok);
            k_accum<<<K * s3, BLK, 0, stream>>>(
                queue_p, btot_p, bbase_p, partial_p, s3, r == 0 ? 1 : 0);
        }
        k_final<<<(n_nodes + 255) / 256, 256, 0, stream>>>(
            x, sl, partial_p, (float*)d_out, n_nodes, s3);
        return;
    }

    // ---------------- fallback: verified R4 path ----------------
    float* logsum = (float*)d_ws;
    const bool use_l2 = ws_size >= (size_t)8 * (size_t)n_nodes * sizeof(float);
    const int n_ls = use_l2 ? 8 * n_nodes : n_nodes;

    init_zero<<<(n_ls + 255) / 256, 256, 0, stream>>>(logsum, n_ls);

    const int e4 = n_edges / 4;
    const int tail_start = e4 * 4;
    const int tail = n_edges - tail_start;

    if (use_l2) {
        if (e4 > 0)
            edge_scatter<true><<<(e4 + 255) / 256, 256, 0, stream>>>(
                x, src, dst, probs, w, logsum, n_nodes, e4);
        if (tail > 0)
            edge_scatter_tail<true><<<(tail + 255) / 256, 256, 0, stream>>>(
                x, src, dst, probs, w, logsum, n_nodes, tail_start, n_edges);
        finalize8<<<(n_nodes + 255) / 256, 256, 0, stream>>>(
            x, sl, logsum, (float*)d_out, n_nodes);
    } else {
        if (e4 > 0)
            edge_scatter<false><<<(e4 + 255) / 256, 256, 0, stream>>>(
                x, src, dst, probs, w, logsum, n_nodes, e4);
        if (tail > 0)
            edge_scatter_tail<false><<<(tail + 255) / 256, 256, 0, stream>>>(
                x, src, dst, probs, w, logsum, n_nodes, tail_start, n_edges);
        finalize1<<<(n_nodes + 255) / 256, 256, 0, stream>>>(
            x, sl, logsum, (float*)d_out, n_nodes);
    }
}

// Round 4
// 861.006 us; speedup vs baseline: 2.1452x; 1.1297x over previous
//
#include <hip/hip_runtime.h>

// out[d] = prod_{e: dst[e]==d} (1 - x[src[e]] * p[e] * w)  + sl * x[d]
//
// R8 == R7 resubmit (round 3 failed in the container acquire path, not the
// kernel; audit found no device-side defect). Structure:
//   - k_hist/k_scan_row/k_scan_bkt: exact global binning, no global atomics.
//   - k_scatter: per-block bucket counts derived from the scanned hist
//     (base[k][b+1]-base[k][b]) -> dst read once; (loc,m) pairs staged
//     bucket-grouped in 32KB LDS, flushed with consecutive lanes ->
//     consecutive global slots (coalesced full-line stores, ~8x fewer
//     store transactions than R6's direct scatter).
//   - k_accum: contiguous bucket slab, uint4 loads (2 entries/lane),
//     16B-aligned via even bucket bases/slices, ds_add_f32 into 32KB LDS.
// Fallbacks: multi-round if ws is small; R4 atomic path if ws is tiny.

#if defined(__has_builtin) && __has_builtin(__builtin_amdgcn_exp2f)
#define EXP2F(v) __builtin_amdgcn_exp2f(v)
#else
#define EXP2F(v) exp2f(v)
#endif

#define BLK 256
#define NB_SHIFT 13
#define NB (1 << NB_SHIFT)   // 8192 nodes per bucket (32KB fp32 LDS accumulator)
#define EPB 4096             // edges per hist/scatter block (32KB LDS stage)
#define MAXK 256             // max buckets (n_nodes <= 2M)

// ---------------------------------------------------------------- old path --
__device__ __forceinline__ unsigned xcc_id() {
    return __builtin_amdgcn_s_getreg((31 << 11) | 20) & 7u;
}
__device__ __forceinline__ void atomic_fadd_l2(float* p, float v) {
    asm volatile("global_atomic_add_f32 %0, %1, off" :: "v"(p), "v"(v) : "memory");
}
__device__ __forceinline__ void atomic_fadd_agent(float* p, float v) {
    unsafeAtomicAdd(p, v);
}

__global__ void init_zero(float* __restrict__ ws, int n) {
    int i = blockIdx.x * blockDim.x + threadIdx.x;
    if (i < n) ws[i] = 0.0f;
}

template <bool USE_L2>
__global__ __launch_bounds__(256) void edge_scatter(
        const float* __restrict__ x,
        const int* __restrict__ src,
        const int* __restrict__ dst,
        const float* __restrict__ probs,
        const float* __restrict__ w_ptr,
        float* __restrict__ logsum,
        int n_nodes, int n_e4) {
    const float w = w_ptr[0];
    float* ls = USE_L2 ? (logsum + (size_t)xcc_id() * (size_t)n_nodes) : logsum;
    int i = blockIdx.x * blockDim.x + threadIdx.x;
    if (i >= n_e4) return;
    int4   s = ((const int4*)src)[i];
    int4   d = ((const int4*)dst)[i];
    float4 p = ((const float4*)probs)[i];
    float m0 = __log2f(1.0f - x[s.x] * p.x * w);
    float m1 = __log2f(1.0f - x[s.y] * p.y * w);
    float m2 = __log2f(1.0f - x[s.z] * p.z * w);
    float m3 = __log2f(1.0f - x[s.w] * p.w * w);
    if (USE_L2) {
        atomic_fadd_l2(&ls[d.x], m0); atomic_fadd_l2(&ls[d.y], m1);
        atomic_fadd_l2(&ls[d.z], m2); atomic_fadd_l2(&ls[d.w], m3);
    } else {
        atomic_fadd_agent(&ls[d.x], m0); atomic_fadd_agent(&ls[d.y], m1);
        atomic_fadd_agent(&ls[d.z], m2); atomic_fadd_agent(&ls[d.w], m3);
    }
}

template <bool USE_L2>
__global__ void edge_scatter_tail(
        const float* __restrict__ x,
        const int* __restrict__ src,
        const int* __restrict__ dst,
        const float* __restrict__ probs,
        const float* __restrict__ w_ptr,
        float* __restrict__ logsum,
        int n_nodes, int start, int n_edges) {
    const float w = w_ptr[0];
    float* ls = USE_L2 ? (logsum + (size_t)xcc_id() * (size_t)n_nodes) : logsum;
    int i = start + blockIdx.x * blockDim.x + threadIdx.x;
    if (i >= n_edges) return;
    float m = __log2f(1.0f - x[src[i]] * probs[i] * w);
    if (USE_L2) atomic_fadd_l2(&ls[dst[i]], m);
    else        atomic_fadd_agent(&ls[dst[i]], m);
}

__global__ void finalize8(const float* __restrict__ x,
                          const float* __restrict__ sl_ptr,
                          const float* __restrict__ logsum,
                          float* __restrict__ out, int n) {
    int i = blockIdx.x * blockDim.x + threadIdx.x;
    if (i >= n) return;
    float s = 0.0f;
    #pragma unroll
    for (int r = 0; r < 8; ++r) s += logsum[(size_t)r * n + i];
    out[i] = EXP2F(s) + sl_ptr[0] * x[i];
}

__global__ void finalize1(const float* __restrict__ x,
                          const float* __restrict__ sl_ptr,
                          const float* __restrict__ logsum,
                          float* __restrict__ out, int n) {
    int i = blockIdx.x * blockDim.x + threadIdx.x;
    if (i < n) out[i] = EXP2F(logsum[i]) + sl_ptr[0] * x[i];
}

// ---------------------------------------------------------------- new path --

// Step 1: per-block histogram of dst buckets. hist[k*G0 + b].
__global__ __launch_bounds__(256) void k_hist(
        const int* __restrict__ dstp,
        unsigned* __restrict__ hist,
        int ebase, int ecount, int K, int G0, int vec_ok) {
    __shared__ unsigned h[MAXK];
    const int b = blockIdx.x;
    const int t = threadIdx.x;
    for (int i = t; i < K; i += BLK) h[i] = 0;
    __syncthreads();
    const int begin = ebase + b * EPB;
    const int end   = min(begin + EPB, ebase + ecount);
    if (vec_ok) {
        for (int e0 = begin + t * 4; e0 < end; e0 += BLK * 4) {
            if (e0 + 4 <= end) {
                const int4 d = *(const int4*)(dstp + e0);
                atomicAdd(&h[(unsigned)d.x >> NB_SHIFT], 1u);
                atomicAdd(&h[(unsigned)d.y >> NB_SHIFT], 1u);
                atomicAdd(&h[(unsigned)d.z >> NB_SHIFT], 1u);
                atomicAdd(&h[(unsigned)d.w >> NB_SHIFT], 1u);
            } else {
                for (int e = e0; e < end; ++e)
                    atomicAdd(&h[(unsigned)dstp[e] >> NB_SHIFT], 1u);
            }
        }
    } else {
        for (int e0 = begin + t * 4; e0 < end; e0 += BLK * 4) {
            const int ee = min(e0 + 4, end);
            for (int e = e0; e < ee; ++e)
                atomicAdd(&h[(unsigned)dstp[e] >> NB_SHIFT], 1u);
        }
    }
    __syncthreads();
    for (int i = t; i < K; i += BLK) hist[(size_t)i * G0 + b] = h[i];
}

// Step 2a: in-place exclusive scan of each bucket row; row total -> btot[k].
__global__ __launch_bounds__(256) void k_scan_row(
        unsigned* __restrict__ hist, unsigned* __restrict__ btot,
        int G0, int Gr) {
    __shared__ unsigned wsum[4];
    __shared__ unsigned carry;
    const int k = blockIdx.x;
    const int t = threadIdx.x;
    unsigned* row = hist + (size_t)k * G0;
    if (t == 0) carry = 0;
    __syncthreads();
    for (int c0 = 0; c0 < Gr; c0 += BLK) {
        const unsigned v = (c0 + t < Gr) ? row[c0 + t] : 0u;
        unsigned xs = v;
        #pragma unroll
        for (int o = 1; o < 64; o <<= 1) {
            const unsigned y = __shfl_up(xs, o, 64);
            if ((t & 63) >= o) xs += y;
        }
        if ((t & 63) == 63) wsum[t >> 6] = xs;
        __syncthreads();
        unsigned woff = 0;
        for (int wv = 0; wv < (t >> 6); ++wv) woff += wsum[wv];
        const unsigned ex = xs + woff - v + carry;
        if (c0 + t < Gr) row[c0 + t] = ex;
        const unsigned ctot = wsum[0] + wsum[1] + wsum[2] + wsum[3];
        __syncthreads();
        if (t == 0) carry += ctot;
        __syncthreads();
    }
    if (t == 0) btot[k] = carry;
}

// Step 2b: exclusive scan of EVEN-PADDED bucket totals -> bbase[k] (even).
__global__ __launch_bounds__(256) void k_scan_bkt(
        const unsigned* __restrict__ btot, unsigned* __restrict__ bbase, int K) {
    __shared__ unsigned wsum[4];
    const int t = threadIdx.x;
    const unsigned v = (t < K) ? ((btot[t] + 1u) & ~1u) : 0u;
    unsigned xs = v;
    #pragma unroll
    for (int o = 1; o < 64; o <<= 1) {
        const unsigned y = __shfl_up(xs, o, 64);
        if ((t & 63) >= o) xs += y;
    }
    if ((t & 63) == 63) wsum[t >> 6] = xs;
    __syncthreads();
    unsigned woff = 0;
    for (int wv = 0; wv < (t >> 6); ++wv) woff += wsum[wv];
    if (t < K) bbase[t] = xs + woff - v;
}

// Step 3: fused scatter with LDS staging. Per-block bucket counts come from
// the scanned hist row (no re-histogram). (loc,m) pairs are staged grouped
// by bucket in LDS, then flushed with consecutive lanes -> consecutive
// global slots (coalesced full-line stores).
__global__ __launch_bounds__(256) void k_scatter(
        const float* __restrict__ x,
        const int* __restrict__ src,
        const int* __restrict__ dstp,
        const float* __restrict__ probs,
        const float* __restrict__ w_ptr,
        const unsigned* __restrict__ base,   // scanned hist [K][G0]
        const unsigned* __restrict__ btot,
        const unsigned* __restrict__ bbase,
        uint2* __restrict__ queue,
        int ebase, int ecount, int K, int G0, int Gr, int vec_ok) {
    __shared__ uint2    stage[EPB];          // 32KB
    __shared__ unsigned off_s[MAXK + 1];
    __shared__ unsigned cur_s[MAXK];
    __shared__ unsigned gb2_s[MAXK];         // global base minus local offset
    __shared__ unsigned wsum[4];
    const int b = blockIdx.x;
    const int t = threadIdx.x;
    if (K <= 0) return;

    // per-bucket count for this block = base[k][b+1] - base[k][b]
    unsigned v = 0, gbeg = 0;
    if (t < K) {
        const unsigned cme = base[(size_t)t * G0 + b];
        const unsigned cnx = (b + 1 < Gr) ? base[(size_t)t * G0 + b + 1] : btot[t];
        v = cnx - cme;
        gbeg = bbase[t] + cme;
    }
    // block-wide exclusive scan of v -> local offsets
    unsigned xs = v;
    #pragma unroll
    for (int o = 1; o < 64; o <<= 1) {
        const unsigned y = __shfl_up(xs, o, 64);
        if ((t & 63) >= o) xs += y;
    }
    if ((t & 63) == 63) wsum[t >> 6] = xs;
    __syncthreads();
    unsigned woff = 0;
    for (int wv = 0; wv < (t >> 6); ++wv) woff += wsum[wv];
    const unsigned ex = xs + woff - v;
    if (t < K) {
        off_s[t] = ex;
        cur_s[t] = ex;
        gb2_s[t] = gbeg - ex;   // so global slot = gb2_s[k] + local_index
    }
    if (t == 0) off_s[K] = wsum[0] + wsum[1] + wsum[2] + wsum[3];
    __syncthreads();

    // phase B: read edges once, compute m, place into staged slot
    const float w = w_ptr[0];
    const int begin = ebase + b * EPB;
    const int end   = min(begin + EPB, ebase + ecount);
    auto one = [&](int e) {
        const int dv = dstp[e];
        const float m = __log2f(1.0f - x[src[e]] * probs[e] * w);
        const unsigned kk = (unsigned)dv >> NB_SHIFT;
        const unsigned r = atomicAdd(&cur_s[kk], 1u);
        stage[r] = make_uint2((unsigned)dv & (NB - 1), __float_as_uint(m));
    };
    if (vec_ok) {
        for (int e0 = begin + t * 4; e0 < end; e0 += BLK * 4) {
            if (e0 + 4 <= end) {
                const int4   d  = *(const int4*)(dstp + e0);
                const int4   sv = *(const int4*)(src + e0);
                const float4 pv = *(const float4*)(probs + e0);
                const float m0 = __log2f(1.0f - x[sv.x] * pv.x * w);
                const float m1 = __log2f(1.0f - x[sv.y] * pv.y * w);
                const float m2 = __log2f(1.0f - x[sv.z] * pv.z * w);
                const float m3 = __log2f(1.0f - x[sv.w] * pv.w * w);
                const unsigned r0 = atomicAdd(&cur_s[(unsigned)d.x >> NB_SHIFT], 1u);
                stage[r0] = make_uint2((unsigned)d.x & (NB - 1), __float_as_uint(m0));
                const unsigned r1 = atomicAdd(&cur_s[(unsigned)d.y >> NB_SHIFT], 1u);
                stage[r1] = make_uint2((unsigned)d.y & (NB - 1), __float_as_uint(m1));
                const unsigned r2 = atomicAdd(&cur_s[(unsigned)d.z >> NB_SHIFT], 1u);
                stage[r2] = make_uint2((unsigned)d.z & (NB - 1), __float_as_uint(m2));
                const unsigned r3 = atomicAdd(&cur_s[(unsigned)d.w >> NB_SHIFT], 1u);
                stage[r3] = make_uint2((unsigned)d.w & (NB - 1), __float_as_uint(m3));
            } else {
                for (int e = e0; e < end; ++e) one(e);
            }
        }
    } else {
        for (int e0 = begin + t * 4; e0 < end; e0 += BLK * 4) {
            const int ee = min(e0 + 4, end);
            for (int e = e0; e < ee; ++e) one(e);
        }
    }
    __syncthreads();

    // phase C: coalesced flush. Lanes handle consecutive j -> consecutive
    // global slots within each bucket run.
    const int total = end - begin;
    for (int j = t; j < total; j += BLK) {
        const uint2 e = stage[j];
        int lo = 0, hi = K;
        while (hi - lo > 1) {
            const int mid = (lo + hi) >> 1;
            if ((unsigned)j >= off_s[mid]) lo = mid; else hi = mid;
        }
        queue[(size_t)gb2_s[lo] + (unsigned)j] = e;
    }
}

// Step 4: bucket slab (contiguous, even-aligned) -> 32KB LDS accumulator.
__global__ __launch_bounds__(256) void k_accum(
        const uint2* __restrict__ queue,
        const unsigned* __restrict__ btot,
        const unsigned* __restrict__ bbase,
        float* __restrict__ partial,   // [K*s3][NB]
        int s3, int first) {
    __shared__ float acc[NB];
    const int t = threadIdx.x;
    const int k = blockIdx.x / s3;
    const int s = blockIdx.x % s3;
    for (int i = t; i < NB; i += BLK) acc[i] = 0.0f;
    __syncthreads();
    const unsigned cnt = btot[k];
    unsigned per = (cnt + s3 - 1) / s3;
    per = (per + 1u) & ~1u;                       // even -> 16B-aligned slices
    const unsigned lo = min((unsigned)s * per, cnt);
    const unsigned hi = min(lo + per, cnt);
    const unsigned n = hi - lo;
    const uint2* q = queue + bbase[k] + lo;       // bbase even, lo even
    const uint4* q4 = (const uint4*)q;
    const unsigned n4 = n >> 1;
    for (unsigned p = t; p < n4; p += BLK) {
        const uint4 e = q4[p];
        atomicAdd(&acc[e.x], __uint_as_float(e.y));
        atomicAdd(&acc[e.z], __uint_as_float(e.w));
    }
    if ((n & 1u) && t == 0) {
        const uint2 e = q[n - 1];
        atomicAdd(&acc[e.x], __uint_as_float(e.y));
    }
    __syncthreads();
    float* p = partial + (size_t)blockIdx.x * NB;
    if (first) { for (int j = t; j < NB; j += BLK) p[j] = acc[j]; }
    else       { for (int j = t; j < NB; j += BLK) p[j] += acc[j]; }
}

__global__ __launch_bounds__(256) void k_final(
        const float* __restrict__ x,
        const float* __restrict__ sl_ptr,
        const float* __restrict__ partial,
        float* __restrict__ out, int n, int s3) {
    int i = blockIdx.x * blockDim.x + threadIdx.x;
    if (i >= n) return;
    const int k = i >> NB_SHIFT;
    const int l = i & (NB - 1);
    const float* p = partial + ((size_t)k * s3) * NB + l;
    float ssum = 0.0f;
    for (int r = 0; r < s3; ++r) ssum += p[(size_t)r * NB];
    out[i] = EXP2F(ssum) + sl_ptr[0] * x[i];
}

// ---------------------------------------------------------------- host -----

static inline size_t alignup256(size_t v) { return (v + 255) & ~(size_t)255; }

extern "C" void kernel_launch(void* const* d_in, const int* in_sizes, int n_in,
                              void* d_out, int out_size, void* d_ws, size_t ws_size,
                              hipStream_t stream) {
    const float* x          = (const float*)d_in[0];   // (N,1) fp32
    const int*   edge_index = (const int*)  d_in[1];   // (2,E) int32
    const float* probs      = (const float*)d_in[2];   // (E,)  fp32
    const float* w          = (const float*)d_in[3];   // (1,)
    const float* sl         = (const float*)d_in[4];   // (1,)

    const int n_nodes = in_sizes[0];
    const int n_edges = in_sizes[1] / 2;
    const int* src = edge_index;
    const int* dst = edge_index + n_edges;

    const int K = (n_nodes + NB - 1) >> NB_SHIFT;

    // Fit search: smallest round count R, then largest slice count s3.
    int R = 0, s3 = 0, G0 = 0;
    long long Er = 0;
    size_t off_hist = 0, off_btot = 0, off_bbase = 0, off_queue = 0;
    if (n_nodes > 0 && n_edges > 0 && K >= 1 && K <= MAXK) {
        const int s3cand[5] = {16, 8, 4, 2, 1};
        for (int r = 1; r <= 64 && !R; ++r) {
            long long er = (((long long)n_edges + r - 1) / r + 3) & ~3LL;
            if (er < 4) er = 4;
            int g = (int)((er + EPB - 1) / EPB);
            if (g < 1) g = 1;
            for (int ci = 0; ci < 5; ++ci) {
                const int cs3 = s3cand[ci];
                const size_t pb = (size_t)K * cs3 * NB * sizeof(float);
                const size_t hb = (size_t)K * g * sizeof(unsigned);
                const size_t kb = (size_t)K * sizeof(unsigned);
                const size_t o1 = alignup256(pb);                // hist
                const size_t o2 = o1 + alignup256(hb);           // btot
                const size_t o3 = o2 + alignup256(kb);           // bbase
                const size_t o4 = o3 + alignup256(kb);           // queue
                const size_t tot = o4 + ((size_t)er + 2 * MAXK) * sizeof(uint2);
                if (tot <= ws_size) {
                    R = r; s3 = cs3; G0 = g; Er = er;
                    off_hist = o1; off_btot = o2; off_bbase = o3; off_queue = o4;
                    break;
                }
            }
        }
    }

    if (R > 0) {
        char* wsb = (char*)d_ws;
        float*    partial_p = (float*)wsb;
        unsigned* hist_p    = (unsigned*)(wsb + off_hist);
        unsigned* btot_p    = (unsigned*)(wsb + off_btot);
        unsigned* bbase_p   = (unsigned*)(wsb + off_bbase);
        uint2*    queue_p   = (uint2*)(wsb + off_queue);

        const int vec_ok = ((n_edges & 3) == 0) ? 1 : 0;
        for (int r = 0; r < R; ++r) {
            const long long eb = (long long)r * Er;
            if (eb >= n_edges) break;
            const long long rem = (long long)n_edges - eb;
            const int ec = (int)(rem < Er ? rem : Er);
            const int g = (ec + EPB - 1) / EPB;
            k_hist<<<g, BLK, 0, stream>>>(dst, hist_p, (int)eb, ec, K, G0, vec_ok);
            k_scan_row<<<K, BLK, 0, stream>>>(hist_p, btot_p, G0, g);
            k_scan_bkt<<<1, BLK, 0, stream>>>(btot_p, bbase_p, K);
            k_scatter<<<g, BLK, 0, stream>>>(
                x, src, dst, probs, w, hist_p, btot_p, bbase_p, queue_p,
                (int)eb, ec, K, G0, g, vec_ok);
            k_accum<<<K * s3, BLK, 0, stream>>>(
                queue_p, btot_p, bbase_p, partial_p, s3, r == 0 ? 1 : 0);
        }
        k_final<<<(n_nodes + 255) / 256, 256, 0, stream>>>(
            x, sl, partial_p, (float*)d_out, n_nodes, s3);
        return;
    }

    // ---------------- fallback: verified R4 path ----------------
    float* logsum = (float*)d_ws;
    const bool use_l2 = ws_size >= (size_t)8 * (size_t)n_nodes * sizeof(float);
    const int n_ls = use_l2 ? 8 * n_nodes : n_nodes;

    init_zero<<<(n_ls + 255) / 256, 256, 0, stream>>>(logsum, n_ls);

    const int e4 = n_edges / 4;
    const int tail_start = e4 * 4;
    const int tail = n_edges - tail_start;

    if (use_l2) {
        if (e4 > 0)
            edge_scatter<true><<<(e4 + 255) / 256, 256, 0, stream>>>(
                x, src, dst, probs, w, logsum, n_nodes, e4);
        if (tail > 0)
            edge_scatter_tail<true><<<(tail + 255) / 256, 256, 0, stream>>>(
                x, src, dst, probs, w, logsum, n_nodes, tail_start, n_edges);
        finalize8<<<(n_nodes + 255) / 256, 256, 0, stream>>>(
            x, sl, logsum, (float*)d_out, n_nodes);
    } else {
        if (e4 > 0)
            edge_scatter<false><<<(e4 + 255) / 256, 256, 0, stream>>>(
                x, src, dst, probs, w, logsum, n_nodes, e4);
        if (tail > 0)
            edge_scatter_tail<false><<<(tail + 255) / 256, 256, 0, stream>>>(
                x, src, dst, probs, w, logsum, n_nodes, tail_start, n_edges);
        finalize1<<<(n_nodes + 255) / 256, 256, 0, stream>>>(
            x, sl, logsum, (float*)d_out, n_nodes);
    }
}